// Round 1
// 109.074 us; speedup vs baseline: 1.0510x; 1.0510x over previous
//
#include <hip/hip_runtime.h>
#include <math.h>

#define BB 8
#define NCC 1024
#define NTT 1024
#define HH 128
#define DYY 32
#define NTB 16                   // targets per block (was 32): 512 blocks -> 2 blocks/CU
#define LOG2E 1.44269504088896340736f

// LDS arena: 8704 floats = 34 KB (r10/r11 lesson: stay well under 40 KB so the
// VGPR<=128 class's 16 waves/CU = 2 blocks/CU is LDS-admissible; 2x34=68<=160).
//   phase 1:  hbuf[HB,2064) red[RED,3600) Wbuf[WB,5696) sigl[SIGL,+48)
//   phase 2:  yc tiles [YCS, 2x2048) xc [XCS, 2x192) sigl
//   epilogue: cmb [0,8448) + sl [8448,8704)  (aliases yc/xc; sigl dead by then)
#define HB 0
#define RED 2064
#define WB 3648
#define YCS 0
#define XCS 4096
#define SIGL 8656
#define CMB 0
#define SL 8448
#define SMEM_SZ 8704
#define HSTRIDE 129              // 129 % 32 == 1: ch reads conflict-free

// 512 blocks x 512 threads. Occupancy was the limiter (256 blocks = 1 block/CU,
// 20% occupancy, VALUBusy 32%): halve per-block targets so 2 blocks co-reside
// per CU and fill each other's barrier/prefetch stalls.
// Phase 1 MLP: thread=(jg 0..31, p 0..15), 4 cols. W streamed through LDS in
// 8-k chunks with distance-2 prefetch and ONE barrier per chunk (write of
// chunk c+2 after barrier(c) is ordered against readers by barrier(c+1)).
// Phase 2 attn: 16 tiles of 64 n; lane=(ns,dg,tl): wave w covers n in
// [w*8, w*8+8) split 2-way by ns; dist/exp duplicated only x2 (across dg).
// P<=0 (sig>0) => exp(P)<=1: no max subtraction needed.
__global__ __launch_bounds__(512) void k_fused(const float* __restrict__ xc,
                                               const float* __restrict__ yc,
                                               const float* __restrict__ xt,
                                               const float* __restrict__ W0,
                                               const float* __restrict__ b0,
                                               const float* __restrict__ W1,
                                               const float* __restrict__ b1,
                                               const float* __restrict__ W2,
                                               const float* __restrict__ b2,
                                               const float* __restrict__ W3,
                                               const float* __restrict__ b3,
                                               float* __restrict__ out) {
    const int tid = threadIdx.x;
    const int t0 = blockIdx.x * NTB;     // global target base (xt/out are flat B*Nt)
    const int b = blockIdx.x >> 6;       // 64 blocks per batch

    __shared__ float smem[SMEM_SZ];      // 34 KB

    const float4* __restrict__ ycG = (const float4*)(yc + (size_t)b * NCC * DYY);
    const float4* __restrict__ xcG = (const float4*)(xc + (size_t)b * NCC * 3);

    // ================= phase 1: MLP =================
    {
        const int jg = tid >> 4;         // 0..31 col-group (4 cols)
        const int p = tid & 15;          // 0..15 point
        const int j0 = jg * 4;

        // ---- L0 ----
        const float* xr = xt + (size_t)(t0 + p) * 3;
        float x0 = xr[0], x1 = xr[1], x2 = xr[2];
        float o[4];
#pragma unroll
        for (int jj = 0; jj < 4; ++jj) {
            int j = j0 + jj;
            float a = b0[j];
            a = fmaf(x0, W0[0 * HH + j], a);
            a = fmaf(x1, W0[1 * HH + j], a);
            a = fmaf(x2, W0[2 * HH + j], a);
            o[jj] = fmaxf(a, 0.f);
        }
#pragma unroll
        for (int jj = 0; jj < 4; ++jj) smem[HB + p * HSTRIDE + j0 + jj] = o[jj];

        // ---- L1, L2: W via LDS chunks (8 k-rows = 1024 floats per chunk) ----
        for (int l = 0; l < 2; ++l) {
            const float4* __restrict__ Wv = (const float4*)((l == 0) ? W1 : W2);
            const float* __restrict__ bi = (l == 0) ? b1 : b2;
            float acc[4];
#pragma unroll
            for (int jj = 0; jj < 4; ++jj) acc[jj] = bi[j0 + jj];

            if (tid < 256) {             // stage chunks 0,1 (coalesced float4)
                ((float4*)(smem + WB))[tid] = Wv[tid];
                ((float4*)(smem + WB + 1024))[tid] = Wv[256 + tid];
            }
            __syncthreads();

            for (int c = 0; c < 16; ++c) {
                float4 wpre;
                if (c < 14 && tid < 256) wpre = Wv[(c + 2) * 256 + tid];
                const float* wbuf = smem + WB + (c & 1) * 1024;
#pragma unroll
                for (int kk = 0; kk < 8; ++kk) {
                    const int k = c * 8 + kk;
                    float ch = smem[HB + p * HSTRIDE + k];
                    float4 ca = *(const float4*)(wbuf + kk * HH + j0);
                    acc[0] = fmaf(ch, ca.x, acc[0]);
                    acc[1] = fmaf(ch, ca.y, acc[1]);
                    acc[2] = fmaf(ch, ca.z, acc[2]);
                    acc[3] = fmaf(ch, ca.w, acc[3]);
                }
                __syncthreads();          // chunk reads done
                if (c < 14 && tid < 256)  // write chunk c+2 into freed buffer
                    ((float4*)(smem + WB + (c & 1) * 1024))[tid] = wpre;
            }

#pragma unroll
            for (int jj = 0; jj < 4; ++jj) o[jj] = fmaxf(acc[jj], 0.f);
            if (l == 0) {
#pragma unroll
                for (int jj = 0; jj < 4; ++jj)
                    smem[HB + p * HSTRIDE + j0 + jj] = o[jj];
                __syncthreads();          // h writes visible for layer 2
            }
        }

        // ---- L3 + exp -> sig*log2e in LDS ----
        float p0 = 0.f, p1 = 0.f, p2 = 0.f;
#pragma unroll
        for (int jj = 0; jj < 4; ++jj) {
            int j = j0 + jj;
            p0 = fmaf(o[jj], W3[j * 3 + 0], p0);
            p1 = fmaf(o[jj], W3[j * 3 + 1], p1);
            p2 = fmaf(o[jj], W3[j * 3 + 2], p2);
        }
        smem[RED + (jg * 16 + p) * 3 + 0] = p0;
        smem[RED + (jg * 16 + p) * 3 + 1] = p1;
        smem[RED + (jg * 16 + p) * 3 + 2] = p2;
        __syncthreads();
        if (tid < 48) {
            int r = tid / 3, cidx = tid - r * 3;
            float v = b3[cidx];
#pragma unroll
            for (int g = 0; g < 32; ++g) v += smem[RED + (g * 16 + r) * 3 + cidx];
            smem[SIGL + r * 3 + cidx] = __expf(v) * LOG2E;
        }
        __syncthreads();                  // sigl ready; hbuf/red/Wbuf now dead
    }

    // ================= phase 2: attention (16 tiles of 64 n) =================
    const int w = tid >> 6;          // 0..7 wave
    const int lane = tid & 63;
    const int tl = lane & 15;        // target within block
    const int dg = (lane >> 4) & 1;  // d-half (16 floats)
    const int ns = lane >> 5;        // n sub-split within the wave's 8 n

    const float s0 = smem[SIGL + tl * 3 + 0];
    const float s1 = smem[SIGL + tl * 3 + 1];
    const float s2 = smem[SIGL + tl * 3 + 2];
    const float* ar = xt + (size_t)(t0 + tl) * 3;
    const float a0 = ar[0], a1 = ar[1], a2 = ar[2];

    float acc[16];
#pragma unroll
    for (int i = 0; i < 16; ++i) acc[i] = 0.f;
    float l = 0.f;

    // stage tiles 0,1 (yc: 512 float4/tile; xc: 48 float4/tile)
    {
        float4 y0 = ycG[tid], y1 = ycG[512 + tid];
        float4 xq0, xq1;
        if (tid < 48) { xq0 = xcG[tid]; xq1 = xcG[48 + tid]; }
        ((float4*)(smem + YCS))[tid] = y0;
        ((float4*)(smem + YCS + 2048))[tid] = y1;
        if (tid < 48) {
            ((float4*)(smem + XCS))[tid] = xq0;
            ((float4*)(smem + XCS + 192))[tid] = xq1;
        }
    }
    __syncthreads();

    for (int tile = 0; tile < 16; ++tile) {
        float4 yn, xn;
        if (tile < 14) {                  // prefetch tile+2 (distance 2)
            yn = ycG[(tile + 2) * 512 + tid];
            if (tid < 48) xn = xcG[(tile + 2) * 48 + tid];
        }

        const float* yb = smem + YCS + (tile & 1) * 2048;
        const float* xb = smem + XCS + (tile & 1) * 192;
#pragma unroll
        for (int i = 0; i < 4; ++i) {
            const int nn = w * 8 + ns * 4 + i;
            float d0 = xb[nn * 3 + 0] - a0;
            float d1 = xb[nn * 3 + 1] - a1;
            float d2 = xb[nn * 3 + 2] - a2;
            float pp = fmaf(s0, d0 * d0, fmaf(s1, d1 * d1, s2 * (d2 * d2)));
            float e = exp2f(-pp);
            l += e;
            const float4* yv = (const float4*)(yb + nn * DYY + dg * 16);
            float4 q0 = yv[0], q1 = yv[1], q2 = yv[2], q3 = yv[3];
            acc[0]  = fmaf(e, q0.x, acc[0]);
            acc[1]  = fmaf(e, q0.y, acc[1]);
            acc[2]  = fmaf(e, q0.z, acc[2]);
            acc[3]  = fmaf(e, q0.w, acc[3]);
            acc[4]  = fmaf(e, q1.x, acc[4]);
            acc[5]  = fmaf(e, q1.y, acc[5]);
            acc[6]  = fmaf(e, q1.z, acc[6]);
            acc[7]  = fmaf(e, q1.w, acc[7]);
            acc[8]  = fmaf(e, q2.x, acc[8]);
            acc[9]  = fmaf(e, q2.y, acc[9]);
            acc[10] = fmaf(e, q2.z, acc[10]);
            acc[11] = fmaf(e, q2.w, acc[11]);
            acc[12] = fmaf(e, q3.x, acc[12]);
            acc[13] = fmaf(e, q3.y, acc[13]);
            acc[14] = fmaf(e, q3.z, acc[14]);
            acc[15] = fmaf(e, q3.w, acc[15]);
        }
        __syncthreads();                  // tile reads done
        if (tile < 14) {                  // write tile+2 into the freed buffer;
            ((float4*)(smem + YCS + (tile & 1) * 2048))[tid] = yn;   // readers are
            if (tid < 48)                                            // fenced by the
                ((float4*)(smem + XCS + (tile & 1) * 192))[tid] = xn; // next barrier
        }
    }

    // ---- single-stage 16-slot combine (stride 33), normalize, write ----
    {
        const int slot = w * 2 + ns;      // 16 partial sets
#pragma unroll
        for (int i = 0; i < 16; ++i)
            smem[CMB + (slot * 16 + tl) * 33 + dg * 16 + i] = acc[i];
        if (dg == 0) smem[SL + slot * 16 + tl] = l;
    }
    __syncthreads();
    {
        const int rtl = tid >> 5, d = tid & 31;   // each thread owns one output
        float s = 0.f, lsum = 0.f;
#pragma unroll
        for (int sl_ = 0; sl_ < 16; ++sl_) {
            s += smem[CMB + (sl_ * 16 + rtl) * 33 + d];
            lsum += smem[SL + sl_ * 16 + rtl];
        }
        out[(size_t)(t0 + rtl) * DYY + d] = s / lsum;
    }
}

extern "C" void kernel_launch(void* const* d_in, const int* in_sizes, int n_in,
                              void* d_out, int out_size, void* d_ws, size_t ws_size,
                              hipStream_t stream) {
    const float* xc = (const float*)d_in[0];
    const float* yc = (const float*)d_in[1];
    const float* xt = (const float*)d_in[2];
    const float* W0 = (const float*)d_in[3];
    const float* b0 = (const float*)d_in[4];
    const float* W1 = (const float*)d_in[5];
    const float* b1 = (const float*)d_in[6];
    const float* W2 = (const float*)d_in[7];
    const float* b2 = (const float*)d_in[8];
    const float* W3 = (const float*)d_in[9];
    const float* b3 = (const float*)d_in[10];
    float* out = (float*)d_out;

    k_fused<<<dim3(BB * NTT / NTB), dim3(512), 0, stream>>>(xc, yc, xt, W0, b0,
                                                            W1, b1, W2, b2, W3,
                                                            b3, out);
}